// Round 4
// baseline (3089.607 us; speedup 1.0000x reference)
//
#include <hip/hip_runtime.h>
#include <hip/hip_bf16.h>
#include <stdint.h>
#include <stddef.h>

#define VOCAB 32000
#define HID 256
#define BATCH 16
#define SEQ 256
#define TSTEPS 255          // S-1
#define NGATES 1024         // 4*HID
#define NWG 2               // scan workgroups (each owns 128 hidden units)
#define MROWS (TSTEPS*BATCH) // 4080

typedef __attribute__((ext_vector_type(8))) __bf16 bf16x8;
typedef __attribute__((ext_vector_type(8))) short short8;
typedef __attribute__((ext_vector_type(4))) float floatx4;
typedef __attribute__((ext_vector_type(4))) uint32_t uint32x4;

__device__ __forceinline__ float sigmoidf_(float x) {
    return 1.0f / (1.0f + __expf(-x));
}
__device__ __forceinline__ float tanhf_(float x) {
    return 2.0f / (1.0f + __expf(-2.0f * x)) - 1.0f;
}

// load 8 consecutive f32 (32B-aligned) -> bf16x8 fragment
__device__ __forceinline__ bf16x8 cvt8(const float* __restrict__ p) {
    const floatx4* q = (const floatx4*)p;
    floatx4 x = q[0], y = q[1];
    bf16x8 r;
    r[0] = (__bf16)x[0]; r[1] = (__bf16)x[1]; r[2] = (__bf16)x[2]; r[3] = (__bf16)x[3];
    r[4] = (__bf16)y[0]; r[5] = (__bf16)y[1]; r[6] = (__bf16)y[2]; r[7] = (__bf16)y[3];
    return r;
}

// step-tag for self-validating packed h words.
// hi/lo bytes always differ (0xC3 != 0x5A), so no uniform-byte workspace
// poison pattern can alias any tag.
__device__ __forceinline__ uint32_t tag16(int t) {
    return (uint32_t)((((t ^ 0xC3) & 0xFF) << 8) | ((t ^ 0x5A) & 0xFF));
}

// ---------------- K0: f32 -> bf16 convert (W_lin, W_ih) ----------------
__global__ __launch_bounds__(256) void k_cvt(const float* __restrict__ src,
                                             __bf16* __restrict__ dst) {
    size_t i = ((size_t)blockIdx.x * 256 + threadIdx.x) * 8;
    bf16x8 r = cvt8(src + i);
    *(bf16x8*)(dst + i) = r;
}

// ---------------- K1: xw[t][n][b] = emb_eff[tok[b][t]] @ W_ih.T + b_ih + b_hh
__global__ __launch_bounds__(256) void k_xw(const int* __restrict__ old,
                                            const float* __restrict__ emb,
                                            const __bf16* __restrict__ wih,
                                            const float* __restrict__ b_ih,
                                            const float* __restrict__ b_hh,
                                            float* __restrict__ xw) {
    int t = blockIdx.x;
    int tid = threadIdx.x;
    int wave = tid >> 6, lane = tid & 63, quad = lane >> 4, l16 = lane & 15;

    int tok = old[l16 * SEQ + t];
    bf16x8 a[8];
#pragma unroll
    for (int kt = 0; kt < 8; kt++) {
        if (tok == 0) {
            bf16x8 z;
#pragma unroll
            for (int j = 0; j < 8; j++) z[j] = (__bf16)0.0f;
            a[kt] = z;
        } else {
            a[kt] = cvt8(emb + (size_t)tok * HID + kt * 32 + quad * 8);
        }
    }

    float* xwt = xw + (size_t)t * NGATES * BATCH;
    for (int nt = 0; nt < 16; nt++) {
        int n = wave * 256 + nt * 16 + l16;
        floatx4 acc = {0.0f, 0.0f, 0.0f, 0.0f};
#pragma unroll
        for (int kt = 0; kt < 8; kt++) {
            bf16x8 bf = *(const bf16x8*)(wih + (size_t)n * HID + kt * 32 + quad * 8);
            acc = __builtin_amdgcn_mfma_f32_16x16x32_bf16(a[kt], bf, acc, 0, 0, 0);
        }
        float bias = b_ih[n] + b_hh[n];
        acc[0] += bias; acc[1] += bias; acc[2] += bias; acc[3] += bias;
        *(floatx4*)(xwt + n * BATCH + quad * 4) = acc;
    }
}

// ---------------- K2: the LSTM scan ----------------
// 2 WGs x 512 threads (8 waves). WG g owns hidden cols [128g, 128g+128);
// wave w owns 16 of them. W_hh fragments live in VGPRs (128 VGPR/wave).
//
// h exchange:
//  - LOCAL half (own 128 cols): plain bf16 in LDS (XOR-swizzled), made
//    visible by the per-step __syncthreads. Zero fabric traffic.
//  - REMOTE half: producer publishes packed (tag(t)<<16)|bf16 words into a
//    CONSUMER-LINEAR per-(t,wg) 8KB block via relaxed agent atomic stores
//    (write-through, fire-and-forget). ONE poller wave (wave 0) per WG
//    polls that block with 8 perfectly-coalesced global_load_dwordx4
//    (sc0 sc1, single vmcnt(0) inside asm), validates every word's tag,
//    unpacks into LDS, and raises an LDS flag (release). Other waves
//    overlap local MFMAs with the poll and spin only on the LDS flag.
// No fences, no contended flag cachelines, no cross-WG barriers.
// Slots are write-once per t (256 distinct blocks -> no ABA);
// max inter-WG skew is 1 step -> no deadlock cycle exists.
// hpk doubles as k_proj's A input (tags masked there) -> no hbuf stores.
__global__ __launch_bounds__(512, 2) void k_scan(const float* __restrict__ W_hh,
                                                 const float* __restrict__ xw,
                                                 uint32_t* __restrict__ hpk) {
    __shared__ uint16_t h_lds[2 * 16 * 256];  // [slot][row 16][col 256], swizzled
    __shared__ int rflag[2];

    int wg = blockIdx.x;
    int tid = threadIdx.x;
    int wave = tid >> 6, lane = tid & 63, quad = lane >> 4, l16 = lane & 15;
    int jj = wg * 128 + wave * 16 + l16;  // this lane's hidden-unit column
    int cloc = jj & 127;                  // col within own half

    // Preload B fragments: B[k][n] = W_hh[gate*256 + jj][k]
    bf16x8 wf[4][8];
#pragma unroll
    for (int g = 0; g < 4; g++) {
        const float* wrow = W_hh + (size_t)(g * HID + jj) * HID;
#pragma unroll
        for (int kt = 0; kt < 8; kt++)
            wf[g][kt] = cvt8(wrow + kt * 32 + quad * 8);
    }

    // prologue: publish own half of h(0)=0 (tagged), zero local LDS slot 0
    {
        uint32_t z = tag16(0) << 16;
        uint32_t* p0 = hpk + (size_t)wg * 2048;
#pragma unroll
        for (int r = 0; r < 4; r++) {
            int row = quad * 4 + r;
            __hip_atomic_store(p0 + row * 128 + cloc, z,
                               __ATOMIC_RELAXED, __HIP_MEMORY_SCOPE_AGENT);
            int idx = (row * 256 + jj) ^ ((row & 7) << 3);
            h_lds[idx] = 0;
        }
        if (tid < 2) rflag[tid] = 0;
    }
    __syncthreads();

    float cr0 = 0.0f, cr1 = 0.0f, cr2 = 0.0f, cr3 = 0.0f;  // c, b = quad*4 + r

    // xw accumulator init, software-pipelined one step ahead
    floatx4 accN[4];
#pragma unroll
    for (int g = 0; g < 4; g++)
        accN[g] = *(const floatx4*)(xw + (size_t)(g * HID + jj) * BATCH + quad * 4);

    for (int t = 0; t < TSTEPS; t++) {
        int slot = t & 1;
        int sb = slot * 4096;
        floatx4 acc[4];
#pragma unroll
        for (int g = 0; g < 4; g++) acc[g] = accN[g];

        // ---- poller: fetch remote half, validate, unpack into LDS ----
        if (wave == 0) {
            const uint32_t* rb = hpk + ((size_t)t * 2 + (1 - wg)) * 2048 + lane * 4;
            const uint32_t* rb2 = rb + 1024;  // +4096 bytes
            uint32x4 q[8];
            uint32_t texpw = tag16(t) << 16;
            while (true) {
                asm volatile(
                    "global_load_dwordx4 %0, %8, off sc0 sc1\n\t"
                    "global_load_dwordx4 %1, %8, off offset:1024 sc0 sc1\n\t"
                    "global_load_dwordx4 %2, %8, off offset:2048 sc0 sc1\n\t"
                    "global_load_dwordx4 %3, %8, off offset:3072 sc0 sc1\n\t"
                    "global_load_dwordx4 %4, %9, off sc0 sc1\n\t"
                    "global_load_dwordx4 %5, %9, off offset:1024 sc0 sc1\n\t"
                    "global_load_dwordx4 %6, %9, off offset:2048 sc0 sc1\n\t"
                    "global_load_dwordx4 %7, %9, off offset:3072 sc0 sc1\n\t"
                    "s_waitcnt vmcnt(0)"
                    : "=v"(q[0]), "=v"(q[1]), "=v"(q[2]), "=v"(q[3]),
                      "=v"(q[4]), "=v"(q[5]), "=v"(q[6]), "=v"(q[7])
                    : "v"(rb), "v"(rb2)
                    : "memory");
                uint32_t accor = 0;
#pragma unroll
                for (int i = 0; i < 8; i++)
#pragma unroll
                    for (int e = 0; e < 4; e++)
                        accor |= q[i][e] ^ texpw;
                if (!__any((accor & 0xFFFF0000u) != 0)) break;
                __builtin_amdgcn_s_sleep(2);  // back off; don't flood the fabric
            }
            // unpack: lane holds words w = i*256 + lane*4 + e
            //   row = i*2 + (lane>>5), col' = (lane&31)*4 + e
            int l5 = lane & 31, lhi = lane >> 5;
            int cbase = (1 - wg) * 128 + l5 * 4;
#pragma unroll
            for (int i = 0; i < 8; i++) {
                int row = i * 2 + lhi;
                uint32_t v01 = (q[i][0] & 0xFFFFu) | (q[i][1] << 16);
                uint32_t v23 = (q[i][2] & 0xFFFFu) | (q[i][3] << 16);
                int idx = (sb + row * 256 + cbase) ^ ((row & 7) << 3);
                *(uint32_t*)&h_lds[idx] = v01;
                *(uint32_t*)&h_lds[idx + 2] = v23;
            }
            __hip_atomic_store(&rflag[slot], t + 1, __ATOMIC_RELEASE,
                               __HIP_MEMORY_SCOPE_WORKGROUP);
        }

        // ---- local-half MFMAs (own 128 cols, kt in [wg*4, wg*4+4)) ----
#pragma unroll
        for (int ki = 0; ki < 4; ki++) {
            int kt = wg * 4 + ki;
            int idx = (sb + l16 * 256 + kt * 32 + quad * 8) ^ ((l16 & 7) << 3);
            bf16x8 af = *(const bf16x8*)&h_lds[idx];
#pragma unroll
            for (int g = 0; g < 4; g++)
                acc[g] = __builtin_amdgcn_mfma_f32_16x16x32_bf16(af, wf[g][kt], acc[g], 0, 0, 0);
        }

        // prefetch next step's xw while waiting for the remote half
        if (t + 1 < TSTEPS) {
            const float* xwn = xw + (size_t)(t + 1) * NGATES * BATCH;
#pragma unroll
            for (int g = 0; g < 4; g++)
                accN[g] = *(const floatx4*)(xwn + (size_t)(g * HID + jj) * BATCH + quad * 4);
        }

        if (wave != 0) {
            while (__hip_atomic_load(&rflag[slot], __ATOMIC_ACQUIRE,
                                     __HIP_MEMORY_SCOPE_WORKGROUP) != t + 1)
                __builtin_amdgcn_s_sleep(1);
        }

        // ---- remote-half MFMAs ----
#pragma unroll
        for (int ki = 0; ki < 4; ki++) {
            int kt = (1 - wg) * 4 + ki;
            int idx = (sb + l16 * 256 + kt * 32 + quad * 8) ^ ((l16 & 7) << 3);
            bf16x8 af = *(const bf16x8*)&h_lds[idx];
#pragma unroll
            for (int g = 0; g < 4; g++)
                acc[g] = __builtin_amdgcn_mfma_f32_16x16x32_bf16(af, wf[g][kt], acc[g], 0, 0, 0);
        }

        // ---- gates + publish h(t+1) ----
        uint32_t* hpo = hpk + ((size_t)(t + 1) * 2 + wg) * 2048;
        uint32_t otag = tag16(t + 1) << 16;
        int slot2 = (t + 1) & 1;
        float c[4] = {cr0, cr1, cr2, cr3};
#pragma unroll
        for (int r = 0; r < 4; r++) {
            float iv = sigmoidf_(acc[0][r]);
            float fv = sigmoidf_(acc[1][r]);
            float gv = tanhf_(acc[2][r]);
            float ov = sigmoidf_(acc[3][r]);
            float cn = fv * c[r] + iv * gv;
            float h = ov * tanhf_(cn);
            c[r] = cn;
            union { __bf16 b; uint16_t u; } cvb; cvb.b = (__bf16)h;
            int row = quad * 4 + r;
            // local LDS for next step
            int idx = (slot2 * 4096 + row * 256 + jj) ^ ((row & 7) << 3);
            h_lds[idx] = cvb.u;
            // remote packed publish (consumer-linear, also k_proj's A input)
            __hip_atomic_store(hpo + row * 128 + cloc, otag | (uint32_t)cvb.u,
                               __ATOMIC_RELAXED, __HIP_MEMORY_SCOPE_AGENT);
        }
        cr0 = c[0]; cr1 = c[1]; cr2 = c[2]; cr3 = c[3];

        __syncthreads();  // closes the step; makes local LDS half visible
    }
}

// ---------------- K3: logits = hs @ W_lin.T + b_lin ----------------
// A rows m = t*16+b read from hpk slot t+1 (tags masked off in the stage)
#define K3_MT 128
#define K3_NT 128
#define K3_KC 64
#define K3_LDR 72  // shorts per LDS row (+8 pad -> 2-way-max bank aliasing, free)

__global__ __launch_bounds__(256) void k_proj(const uint32_t* __restrict__ hpk,
                                              const __bf16* __restrict__ wl,
                                              const float* __restrict__ b_lin,
                                              float* __restrict__ out) {
    __shared__ short lA[K3_MT * K3_LDR];
    __shared__ short lB[K3_NT * K3_LDR];

    int tid = threadIdx.x;
    int wave = tid >> 6, lane = tid & 63, quad = lane >> 4, l16 = lane & 15;
    int wm = wave >> 1, wn = wave & 1;
    int m0 = blockIdx.y * K3_MT;
    int n0 = blockIdx.x * K3_NT;

    floatx4 acc[4][4];
#pragma unroll
    for (int i = 0; i < 4; i++)
#pragma unroll
        for (int j = 0; j < 4; j++)
            acc[i][j] = (floatx4){0.0f, 0.0f, 0.0f, 0.0f};

    int srow = tid >> 1;         // 0..127
    int scol = (tid & 1) * 32;   // shorts within the 64-wide K chunk

    int m = m0 + srow;
    int s = (m >> 4) + 1, b = m & 15;

    for (int kc = 0; kc < 4; kc++) {
        int kbase = kc * K3_KC;
        // stage A from packed hpk (guard m < 4080); mask tags, pack bf16
        {
#pragma unroll
            for (int i = 0; i < 4; i++) {
                short8 v = (short8)0;
                if (m < MROWS) {
                    int c0 = kbase + scol + i * 8;
                    const uint32_t* hp4 = hpk + ((size_t)s * 2 + (c0 >> 7)) * 2048 +
                                          (size_t)b * 128 + (c0 & 127);
                    uint32x4 d0 = *(const uint32x4*)hp4;
                    uint32x4 d1 = *(const uint32x4*)(hp4 + 4);
                    union { uint32_t u[4]; short8 s8; } pk;
                    pk.u[0] = (d0[0] & 0xFFFFu) | (d0[1] << 16);
                    pk.u[1] = (d0[2] & 0xFFFFu) | (d0[3] << 16);
                    pk.u[2] = (d1[0] & 0xFFFFu) | (d1[1] << 16);
                    pk.u[3] = (d1[2] & 0xFFFFu) | (d1[3] << 16);
                    v = pk.s8;
                }
                *(short8*)&lA[srow * K3_LDR + scol + i * 8] = v;
            }
        }
        // stage B
        {
            const __bf16* src = wl + (size_t)(n0 + srow) * HID + kbase + scol;
#pragma unroll
            for (int i = 0; i < 4; i++)
                *(short8*)&lB[srow * K3_LDR + scol + i * 8] = *(const short8*)(src + i * 8);
        }
        __syncthreads();
#pragma unroll
        for (int kt = 0; kt < 2; kt++) {
            int ko = kt * 32 + quad * 8;
            bf16x8 af[4], bf[4];
#pragma unroll
            for (int mt = 0; mt < 4; mt++)
                af[mt] = *(bf16x8*)&lA[(wm * 64 + mt * 16 + l16) * K3_LDR + ko];
#pragma unroll
            for (int nt = 0; nt < 4; nt++)
                bf[nt] = *(bf16x8*)&lB[(wn * 64 + nt * 16 + l16) * K3_LDR + ko];
#pragma unroll
            for (int mt = 0; mt < 4; mt++)
#pragma unroll
                for (int nt = 0; nt < 4; nt++)
                    acc[mt][nt] = __builtin_amdgcn_mfma_f32_16x16x32_bf16(
                        af[mt], bf[nt], acc[mt][nt], 0, 0, 0);
        }
        __syncthreads();
    }

    // epilogue: out[b][t][v], m = t*16 + b
#pragma unroll
    for (int nt = 0; nt < 4; nt++) {
        int n = n0 + wn * 64 + nt * 16 + l16;
        float bias = b_lin[n];
#pragma unroll
        for (int mt = 0; mt < 4; mt++) {
            int mbase = m0 + wm * 64 + mt * 16 + quad * 4;
#pragma unroll
            for (int r = 0; r < 4; r++) {
                int mm = mbase + r;
                if (mm < MROWS) {
                    int bb = mm & 15, tt = mm >> 4;
                    out[(size_t)bb * TSTEPS * VOCAB + (size_t)tt * VOCAB + n] =
                        acc[mt][nt][r] + bias;
                }
            }
        }
    }
}

// ---------------- launch ----------------
extern "C" void kernel_launch(void* const* d_in, const int* in_sizes, int n_in,
                              void* d_out, int out_size, void* d_ws, size_t ws_size,
                              hipStream_t stream) {
    const int*   old   = (const int*)d_in[0];
    const float* emb   = (const float*)d_in[1];
    const float* W_ih  = (const float*)d_in[2];
    const float* W_hh  = (const float*)d_in[3];
    const float* b_ih  = (const float*)d_in[4];
    const float* b_hh  = (const float*)d_in[5];
    const float* W_lin = (const float*)d_in[6];
    const float* b_lin = (const float*)d_in[7];
    float* out = (float*)d_out;

    char* ws = (char*)d_ws;
    // ws layout (all 16B aligned)
    float*    xw  = (float*)ws;                                   // 255*1024*16*4 = 16,711,680
    __bf16*   wl  = (__bf16*)(ws + 16711680);                     // 32000*256*2   = 16,384,000
    __bf16*   wih = (__bf16*)(ws + 16711680 + 16384000);          // 1024*256*2    =    524,288
    uint32_t* hpk = (uint32_t*)(ws + 16711680 + 16384000 + 524288); // 256 slots * 2 * 8KB = 4,194,304

    // no memsets: hpk slot 0 is published (tagged) by k_scan's prologue,
    // LDS flags are initialized in-kernel, and poison cannot alias tag16.
    k_cvt<<<dim3(VOCAB * HID / 2048), dim3(256), 0, stream>>>(W_lin, wl);
    k_cvt<<<dim3(NGATES * HID / 2048), dim3(256), 0, stream>>>(W_ih, wih);
    k_xw<<<dim3(TSTEPS), dim3(256), 0, stream>>>(old, emb, wih, b_ih, b_hh, xw);
    k_scan<<<dim3(NWG), dim3(512), 0, stream>>>(W_hh, xw, hpk);
    k_proj<<<dim3(VOCAB / K3_NT, (MROWS + K3_MT - 1) / K3_MT), dim3(256), 0, stream>>>(
        hpk, wl, b_lin, out);
}